// Round 2
// baseline (868.099 us; speedup 1.0000x reference)
//
#include <hip/hip_runtime.h>
#include <hip/hip_bf16.h>

#define N_ 32
#define C_ 128
#define H_ 48
#define W_ 48
#define P_ (H_*W_)   // 2304
#define K_ 64
#define S_ 4
#define L_ 3
#define R_ 21

typedef __hip_bfloat16 bf16;

__device__ __forceinline__ float b2f(bf16 v){ return __bfloat162float(v); }
__device__ __forceinline__ float u2f(unsigned short u){
  union { unsigned i; float f; } v; v.i = ((unsigned)u) << 16; return v.f;
}

// ---------- dtype probe: flag=1 if inputs are fp32, 0 if bf16 ----------
__global__ __launch_bounds__(256) void k_probe(const unsigned short* __restrict__ xb,
                                               int* __restrict__ flag){
  int t = threadIdx.x;
  int weird = 0;
  for (int i = t; i < 4096; i += 256){
    int e = (xb[i] >> 7) & 0xFF;
    if (e >= 0x8E) weird++;            // |value| >= 2^15: impossible for N(0,1) bf16
  }
  __shared__ int s[256];
  s[t] = weird; __syncthreads();
  for (int o = 128; o > 0; o >>= 1){ if (t < o) s[t] += s[t+o]; __syncthreads(); }
  if (t == 0) flag[0] = (s[0] > 64) ? 1 : 0;
}

// ---------- K1: per-pixel L2 norm; xn stored bf16 [n][c][p] ----------
__global__ __launch_bounds__(256) void k_norm(const void* __restrict__ x,
                                              const int* __restrict__ flag,
                                              bf16* __restrict__ xn){
  int idx = blockIdx.x*256 + threadIdx.x;       // n*P + p
  int n = idx / P_, p = idx - n*P_;
  int f32 = flag[0];
  float ss = 0.f;
  bf16* xo = xn + (size_t)n*C_*P_ + p;
  if (f32){
    const float* xc = (const float*)x + (size_t)n*C_*P_ + p;
    #pragma unroll 8
    for (int c=0;c<C_;++c){ float v = xc[(size_t)c*P_]; ss += v*v; }
    float invn = 1.f / fmaxf(sqrtf(ss), 1e-12f);
    #pragma unroll 8
    for (int c=0;c<C_;++c) xo[(size_t)c*P_] = __float2bfloat16(xc[(size_t)c*P_] * invn);
  } else {
    const bf16* xc = (const bf16*)x + (size_t)n*C_*P_ + p;
    #pragma unroll 8
    for (int c=0;c<C_;++c){ float v = b2f(xc[(size_t)c*P_]); ss += v*v; }
    float invn = 1.f / fmaxf(sqrtf(ss), 1e-12f);
    #pragma unroll 8
    for (int c=0;c<C_;++c) xo[(size_t)c*P_] = __float2bfloat16(b2f(xc[(size_t)c*P_]) * invn);
  }
}

// ---------- K2: a = softmax_k(conv_w @ xn), stored bf16 ----------
__global__ __launch_bounds__(256) void k_score(const bf16* __restrict__ xn,
                                               const void* __restrict__ cvw,
                                               const int* __restrict__ flag,
                                               bf16* __restrict__ a){
  __shared__ float wsh[K_][C_];                  // 32 KB
  int n = blockIdx.y, t = threadIdx.x;
  int p = blockIdx.x*256 + t;
  int f32 = flag[0];
  if (f32){
    const float* w = (const float*)cvw;
    for (int i=t;i<K_*C_;i+=256) wsh[i>>7][i&127] = w[i];
  } else {
    const bf16* w = (const bf16*)cvw;
    for (int i=t;i<K_*C_;i+=256) wsh[i>>7][i&127] = b2f(w[i]);
  }
  __syncthreads();
  const bf16* xc = xn + (size_t)n*C_*P_ + p;
  float acc[K_];
  #pragma unroll
  for (int k=0;k<K_;++k) acc[k]=0.f;
  for (int c4=0;c4<C_;c4+=4){
    float x0=b2f(xc[(size_t)c4*P_]),     x1=b2f(xc[(size_t)(c4+1)*P_]);
    float x2=b2f(xc[(size_t)(c4+2)*P_]), x3=b2f(xc[(size_t)(c4+3)*P_]);
    #pragma unroll
    for (int k=0;k<K_;++k){
      const float4 w4 = *(const float4*)&wsh[k][c4];
      acc[k] += w4.x*x0 + w4.y*x1 + w4.z*x2 + w4.w*x3;
    }
  }
  float m = -1e30f;
  #pragma unroll
  for (int k=0;k<K_;++k) m = fmaxf(m, acc[k]);
  float Z = 0.f;
  #pragma unroll
  for (int k=0;k<K_;++k){ acc[k] = __expf(acc[k]-m); Z += acc[k]; }
  float invZ = 1.f / Z;
  bf16* ap = a + ((size_t)n*K_)*P_ + p;
  #pragma unroll
  for (int k=0;k<K_;++k) ap[(size_t)k*P_] = __float2bfloat16(acc[k]*invZ);
}

// ---------- K3: shadow softmax; recomputes the 16 scores it needs; a *= sal_pix ----------
__global__ __launch_bounds__(256) void k_shadow(const bf16* __restrict__ xn,
                                                const void* __restrict__ csw,
                                                const void* __restrict__ cvw,
                                                const int* __restrict__ flag,
                                                bf16* __restrict__ a){
  __shared__ float wsh[80][C_];                  // 40 KB: rows 0..63 shadow, 64..79 score
  int n = blockIdx.z, kg = blockIdx.y, t = threadIdx.x;
  int p = blockIdx.x*256 + t;
  int f32 = flag[0];
  if (f32){
    const float* ws_ = (const float*)csw; const float* wv_ = (const float*)cvw;
    for (int i=t;i<80*C_;i+=256){
      int r = i>>7, c = i&127;
      wsh[r][c] = (r < 64) ? ws_[(size_t)kg*64*C_ + i]
                           : wv_[(size_t)(kg*16 + (r-64))*C_ + c];
    }
  } else {
    const bf16* ws_ = (const bf16*)csw; const bf16* wv_ = (const bf16*)cvw;
    for (int i=t;i<80*C_;i+=256){
      int r = i>>7, c = i&127;
      wsh[r][c] = (r < 64) ? b2f(ws_[(size_t)kg*64*C_ + i])
                           : b2f(wv_[(size_t)(kg*16 + (r-64))*C_ + c]);
    }
  }
  __syncthreads();
  const bf16* xc = xn + (size_t)n*C_*P_ + p;
  float acc[80];
  #pragma unroll
  for (int r=0;r<80;++r) acc[r]=0.f;
  for (int c4=0;c4<C_;c4+=4){
    float x0=b2f(xc[(size_t)c4*P_]),     x1=b2f(xc[(size_t)(c4+1)*P_]);
    float x2=b2f(xc[(size_t)(c4+2)*P_]), x3=b2f(xc[(size_t)(c4+3)*P_]);
    #pragma unroll
    for (int r=0;r<80;++r){
      const float4 w4 = *(const float4*)&wsh[r][c4];
      acc[r] += w4.x*x0 + w4.y*x1 + w4.z*x2 + w4.w*x3;
    }
  }
  #pragma unroll
  for (int kl=0;kl<16;++kl){
    int k = kg*16 + kl;
    float s0 = acc[64+kl];
    float m = s0;
    #pragma unroll
    for (int s=0;s<4;++s) m = fmaxf(m, acc[kl*4+s]);
    float e0 = __expf(s0 - m);
    float den = e0;
    #pragma unroll
    for (int s=0;s<4;++s) den += __expf(acc[kl*4+s] - m);
    bf16* ap = a + ((size_t)n*K_+k)*P_ + p;
    *ap = __float2bfloat16(b2f(*ap) * (e0/den));
  }
}

// ---------- K4: per-level app conv + relu -> g bf16 [n][l][k][p] ----------
__global__ __launch_bounds__(256) void k_app(const bf16* __restrict__ xn,
                                             const void* __restrict__ caw,
                                             const int* __restrict__ flag,
                                             bf16* __restrict__ g){
  __shared__ float wsh[K_][C_];
  int n = blockIdx.z, l = blockIdx.y, t = threadIdx.x;
  int p = blockIdx.x*256 + t;
  int f32 = flag[0];
  if (f32){
    const float* w = (const float*)caw + (size_t)l*K_*C_;
    for (int i=t;i<K_*C_;i+=256) wsh[i>>7][i&127] = w[i];
  } else {
    const bf16* w = (const bf16*)caw + (size_t)l*K_*C_;
    for (int i=t;i<K_*C_;i+=256) wsh[i>>7][i&127] = b2f(w[i]);
  }
  __syncthreads();
  const bf16* xc = xn + (size_t)n*C_*P_ + p;
  float acc[K_];
  #pragma unroll
  for (int k=0;k<K_;++k) acc[k]=0.f;
  for (int c4=0;c4<C_;c4+=4){
    float x0=b2f(xc[(size_t)c4*P_]),     x1=b2f(xc[(size_t)(c4+1)*P_]);
    float x2=b2f(xc[(size_t)(c4+2)*P_]), x3=b2f(xc[(size_t)(c4+3)*P_]);
    #pragma unroll
    for (int k=0;k<K_;++k){
      const float4 w4 = *(const float4*)&wsh[k][c4];
      acc[k] += w4.x*x0 + w4.y*x1 + w4.z*x2 + w4.w*x3;
    }
  }
  bf16* gp = g + (((size_t)n*L_ + l)*K_)*P_ + p;
  #pragma unroll
  for (int k=0;k<K_;++k) gp[(size_t)k*P_] = __float2bfloat16(fmaxf(acc[k], 0.f));
}

// ---------- K5: region rectangle sums -> sal fp32 [n][k][21] ----------
__global__ __launch_bounds__(256) void k_sal(const bf16* __restrict__ g, float* __restrict__ sal){
  int tid = blockIdx.x*256 + threadIdx.x;
  if (tid >= N_*K_*R_) return;
  int r = tid % R_; int k = (tid / R_) % K_; int n = tid / (R_*K_);
  int l, rh0, rh1, rw0, rw1;
  if (r == 0){ l=0; rh0=0; rh1=48; rw0=0; rw1=48; }
  else if (r < 5){ l=1; int q=r-1; int i=q>>1, j=q&1;
    rh0=16*i; rh1=16*i+32; rw0=16*j; rw1=16*j+32; }
  else { l=2; int q=r-5; int i=q>>2, j=q&3;
    rh0=max(10*i-1,0); rh1=min(10*i+19,48); rw0=max(10*j-1,0); rw1=min(10*j+19,48); }
  const bf16* gp = g + (((size_t)n*L_+l)*K_+k)*P_;
  float s = 0.f;
  for (int h=rh0;h<rh1;++h){
    const bf16* row = gp + h*W_;
    for (int w=rw0;w<rw1;++w) s += b2f(row[w]);
  }
  sal[((size_t)n*K_+k)*R_ + r] = s;
}

// ---------- K6: vlad[n,k,c] = sum_p a*w*xn - centroid * sum(a*w) ----------
__global__ __launch_bounds__(256) void k_vlad(const bf16* __restrict__ xn,
                                              const bf16* __restrict__ a,
                                              const float* __restrict__ sal,
                                              const void* __restrict__ cen,
                                              const int* __restrict__ flag,
                                              float* __restrict__ vlad){
  __shared__ __align__(16) float s_aw[P_];
  __shared__ float s_sal[R_];
  __shared__ float s_red[256];
  __shared__ float s_sumaw;
  int k = blockIdx.x, n = blockIdx.y, t = threadIdx.x;
  int f32 = flag[0];
  if (t < R_) s_sal[t] = sal[((size_t)n*K_+k)*R_ + t];
  if (t == 0) s_sumaw = 0.f;
  __syncthreads();
  const bf16* ap = a + ((size_t)n*K_+k)*P_;
  float local = 0.f;
  #pragma unroll
  for (int jj=0;jj<9;++jj){
    int p = t + jj*256;
    int h = p/48, wc = p - h*48;
    float wv = s_sal[0];
    #pragma unroll
    for (int i=0;i<2;++i) if (h>=16*i && h<16*i+32) {
      #pragma unroll
      for (int j=0;j<2;++j) if (wc>=16*j && wc<16*j+32) wv += s_sal[1+i*2+j];
    }
    #pragma unroll
    for (int i=0;i<4;++i) if (h>=10*i-1 && h<10*i+19) {
      #pragma unroll
      for (int j=0;j<4;++j) if (wc>=10*j-1 && wc<10*j+19) wv += s_sal[5+i*4+j];
    }
    float aw = b2f(ap[p])*wv;
    s_aw[p] = aw;
    local += aw;
  }
  atomicAdd(&s_sumaw, local);
  __syncthreads();
  int c = t & 127, half = t >> 7;
  const unsigned short* xr = (const unsigned short*)xn + ((size_t)n*C_+c)*P_ + half*(P_/2);
  const float4* a4 = (const float4*)(s_aw + half*(P_/2));
  float acc = 0.f;
  for (int q=0;q<P_/8;++q){                       // 288 ushort4 per half
    ushort4 xv = ((const ushort4*)xr)[q];
    float4 av = a4[q];
    acc += u2f(xv.x)*av.x + u2f(xv.y)*av.y + u2f(xv.z)*av.z + u2f(xv.w)*av.w;
  }
  s_red[t] = acc;
  __syncthreads();
  if (t < 128){
    float cv;
    if (f32) cv = ((const float*)cen)[k*C_ + t];
    else     cv = b2f(((const bf16*)cen)[k*C_ + t]);
    float v = s_red[t] + s_red[t+128] - cv * s_sumaw;
    vlad[((size_t)n*K_+k)*C_ + t] = v;
  }
}

// ---------- K7: intra-norm * cluster_weights, global L2 norm, store (dtype per flag) ----------
__global__ __launch_bounds__(256) void k_final(const float* __restrict__ vlad,
                                               const void* __restrict__ clw,
                                               const int* __restrict__ flag,
                                               void* __restrict__ out){
  __shared__ float s_v[K_*C_];                   // 32 KB
  __shared__ float s_ssk[K_];
  __shared__ float s_scale[K_];
  __shared__ float s_gs;
  int n = blockIdx.x, t = threadIdx.x;
  int f32 = flag[0];
  const float* vp = vlad + (size_t)n*K_*C_;
  for (int i=t;i<K_*C_;i+=256) s_v[i] = vp[i];
  __syncthreads();
  int k = t >> 2, q = t & 3;
  float ss = 0.f;
  for (int m=0;m<32;++m){ float v = s_v[k*C_ + q + 4*m]; ss += v*v; }
  ss += __shfl_down(ss, 2);
  ss += __shfl_down(ss, 1);
  if (q == 0) s_ssk[k] = ss;
  __syncthreads();
  if (t < K_){
    float cw;
    if (f32) cw = ((const float*)clw)[t];
    else     cw = b2f(((const bf16*)clw)[t]);
    s_scale[t] = cw / fmaxf(sqrtf(s_ssk[t]), 1e-12f);
  }
  __syncthreads();
  if (t == 0){
    float gss = 0.f;
    for (int kk=0;kk<K_;++kk) gss += s_ssk[kk]*s_scale[kk]*s_scale[kk];
    s_gs = 1.f / fmaxf(sqrtf(gss), 1e-12f);
  }
  __syncthreads();
  float gsc = s_gs;
  if (f32){
    float* op = (float*)out + (size_t)n*K_*C_;
    for (int i=t;i<K_*C_;i+=256) op[i] = s_v[i]*s_scale[i>>7]*gsc;
  } else {
    bf16* op = (bf16*)out + (size_t)n*K_*C_;
    for (int i=t;i<K_*C_;i+=256) op[i] = __float2bfloat16(s_v[i]*s_scale[i>>7]*gsc);
  }
}

extern "C" void kernel_launch(void* const* d_in, const int* in_sizes, int n_in,
                              void* d_out, int out_size, void* d_ws, size_t ws_size,
                              hipStream_t stream){
  const void* x   = d_in[0];
  const void* cen = d_in[1];
  const void* cvw = d_in[2];
  const void* csw = d_in[3];
  const void* caw = d_in[4];
  const void* clw = d_in[5];

  char* ws = (char*)d_ws;
  int*  flag = (int*)ws;            ws += 256;
  bf16* xn   = (bf16*)ws;           ws += (size_t)N_*C_*P_*2;      // 18.87 MB
  bf16* a    = (bf16*)ws;           ws += (size_t)N_*K_*P_*2;      //  9.44 MB
  bf16* g    = (bf16*)ws;           ws += (size_t)N_*L_*K_*P_*2;   // 28.31 MB
  float* sal = (float*)ws;          ws += (size_t)N_*K_*R_*4;      //  0.17 MB
  float* vlad= (float*)ws;          ws += (size_t)N_*K_*C_*4;      //  1.05 MB
  // total ~57.8 MB

  k_probe <<<dim3(1),                 256, 0, stream>>>((const unsigned short*)x, flag);
  k_norm  <<<dim3((N_*P_)/256),       256, 0, stream>>>(x, flag, xn);
  k_score <<<dim3(P_/256, N_),        256, 0, stream>>>(xn, cvw, flag, a);
  k_shadow<<<dim3(P_/256, 4, N_),     256, 0, stream>>>(xn, csw, cvw, flag, a);
  k_app   <<<dim3(P_/256, L_, N_),    256, 0, stream>>>(xn, caw, flag, g);
  k_sal   <<<dim3((N_*K_*R_+255)/256),256, 0, stream>>>(g, sal);
  k_vlad  <<<dim3(K_, N_),            256, 0, stream>>>(xn, a, sal, cen, flag, vlad);
  k_final <<<dim3(N_),                256, 0, stream>>>(vlad, clw, flag, out_size ? d_out : d_out);
}

// Round 3
// 404.123 us; speedup vs baseline: 2.1481x; 2.1481x over previous
//
#include <hip/hip_runtime.h>
#include <hip/hip_bf16.h>

#define N_ 32
#define C_ 128
#define H_ 48
#define W_ 48
#define P_ (H_*W_)   // 2304
#define K_ 64
#define S_ 4
#define L_ 3
#define R_ 21
#define NB_ 72       // P_/32 pixel tiles per image
#define M_ 512       // total logit rows

typedef __hip_bfloat16 bf16;
typedef __attribute__((ext_vector_type(8))) short   bf16x8;
typedef __attribute__((ext_vector_type(8))) unsigned short u16x8;
typedef __attribute__((ext_vector_type(4))) float   f32x4;

__device__ __forceinline__ float b2f(bf16 v){ return __bfloat162float(v); }
__device__ __forceinline__ float u2f(unsigned short u){
  union { unsigned i; float f; } v; v.i = ((unsigned)u) << 16; return v.f;
}
__device__ __forceinline__ unsigned short f2u(float f){
  bf16 h = __float2bfloat16(f);
  return *(unsigned short*)&h;
}

// ---------- dtype probe: flag=1 if inputs are fp32, 0 if bf16 ----------
__global__ __launch_bounds__(256) void k_probe(const unsigned short* __restrict__ xb,
                                               int* __restrict__ flag){
  int t = threadIdx.x;
  int weird = 0;
  for (int i = t; i < 4096; i += 256){
    int e = (xb[i] >> 7) & 0xFF;
    if (e >= 0x8E) weird++;
  }
  __shared__ int s[256];
  s[t] = weird; __syncthreads();
  for (int o = 128; o > 0; o >>= 1){ if (t < o) s[t] += s[t+o]; __syncthreads(); }
  if (t == 0) flag[0] = (s[0] > 64) ? 1 : 0;
}

// ---------- build Wall[512][128] bf16: rows 0-63 score, 64-319 shadow, 320-511 app ----------
__global__ __launch_bounds__(256) void k_wall(const void* __restrict__ cvw, const void* __restrict__ csw,
                                              const void* __restrict__ caw, const int* __restrict__ flag,
                                              bf16* __restrict__ Wall){
  int i = blockIdx.x*256 + threadIdx.x;          // 0..65535
  int f32 = flag[0];
  float v;
  if (i < 8192)       v = f32 ? ((const float*)cvw)[i]        : b2f(((const bf16*)cvw)[i]);
  else if (i < 40960) v = f32 ? ((const float*)csw)[i-8192]   : b2f(((const bf16*)csw)[i-8192]);
  else                v = f32 ? ((const float*)caw)[i-40960]  : b2f(((const bf16*)caw)[i-40960]);
  Wall[i] = __float2bfloat16(v);
}

// ---------- K1: per-pixel L2 norm -> xnT[n][p][c] bf16 (pixel-major, MFMA-B-ready) ----------
__global__ __launch_bounds__(256) void k_norm(const void* __restrict__ x,
                                              const int* __restrict__ flag,
                                              bf16* __restrict__ xnT){
  int idx = blockIdx.x*256 + threadIdx.x;        // n*P + p
  int n = idx / P_, p = idx - n*P_;
  int f32 = flag[0];
  float ss = 0.f;
  if (f32){
    const float* xc = (const float*)x + (size_t)n*C_*P_ + p;
    #pragma unroll 8
    for (int c=0;c<C_;++c){ float v = xc[(size_t)c*P_]; ss += v*v; }
    float invn = 1.f / fmaxf(sqrtf(ss), 1e-12f);
    bf16* xo = xnT + ((size_t)n*P_ + p)*C_;
    for (int c8=0;c8<C_;c8+=8){
      u16x8 pk;
      #pragma unroll
      for (int j=0;j<8;++j) pk[j] = f2u(xc[(size_t)(c8+j)*P_] * invn);
      *(u16x8*)(xo + c8) = pk;
    }
  } else {
    const bf16* xc = (const bf16*)x + (size_t)n*C_*P_ + p;
    #pragma unroll 8
    for (int c=0;c<C_;++c){ float v = b2f(xc[(size_t)c*P_]); ss += v*v; }
    float invn = 1.f / fmaxf(sqrtf(ss), 1e-12f);
    bf16* xo = xnT + ((size_t)n*P_ + p)*C_;
    for (int c8=0;c8<C_;c8+=8){
      u16x8 pk;
      #pragma unroll
      for (int j=0;j<8;++j) pk[j] = f2u(b2f(xc[(size_t)(c8+j)*P_]) * invn);
      *(u16x8*)(xo + c8) = pk;
    }
  }
}

// ---------- K2: fused 512-row MFMA GEMM + softmax/shadow/app epilogue ----------
// grid (NB_=72, N_=32), 256 threads (4 waves). Wave w owns rows [w*128, w*128+128).
__global__ __launch_bounds__(256, 2) void k_gemm(const bf16* __restrict__ Wall,
                                                 const bf16* __restrict__ xnT,
                                                 bf16* __restrict__ a,
                                                 float* __restrict__ salPart){
  __shared__ float ldsL[M_][34];                 // 69632 B (pad 34 -> conflict-light)
  __shared__ float ldsSal[K_][R_];               // 5376 B
  __shared__ float redA[32][8];
  __shared__ float redB[32][8];
  int n = blockIdx.y, pb = blockIdx.x;
  int p0 = pb*32;
  int t = threadIdx.x, w = t>>6, l = t&63;
  for (int i=t;i<K_*R_;i+=256) ((float*)ldsSal)[i] = 0.f;

  int mrow = l&15, quad = l>>4;
  const bf16* Abase = Wall + ((size_t)(w*128 + mrow))*C_ + quad*8;
  const bf16* Bbase = xnT + ((size_t)n*P_ + p0 + mrow)*C_ + quad*8;

  f32x4 acc[8][2];
  #pragma unroll
  for (int rt=0;rt<8;++rt){ acc[rt][0] = (f32x4){0,0,0,0}; acc[rt][1] = (f32x4){0,0,0,0}; }

  #pragma unroll
  for (int k0=0;k0<C_;k0+=32){
    bf16x8 b0 = *(const bf16x8*)(Bbase + k0);
    bf16x8 b1 = *(const bf16x8*)(Bbase + 16*C_ + k0);
    #pragma unroll
    for (int rt=0;rt<8;++rt){
      bf16x8 af = *(const bf16x8*)(Abase + (size_t)rt*16*C_ + k0);
      acc[rt][0] = __builtin_amdgcn_mfma_f32_16x16x32_bf16(af, b0, acc[rt][0], 0,0,0);
      acc[rt][1] = __builtin_amdgcn_mfma_f32_16x16x32_bf16(af, b1, acc[rt][1], 0,0,0);
    }
  }
  // C/D layout: col = lane&15, row = quad*4 + reg  [m89 verified]
  #pragma unroll
  for (int rt=0;rt<8;++rt)
    #pragma unroll
    for (int ct=0;ct<2;++ct)
      #pragma unroll
      for (int r=0;r<4;++r)
        ldsL[w*128 + rt*16 + quad*4 + r][ct*16 + mrow] = acc[rt][ct][r];
  __syncthreads();

  // ---- epilogue: thread t -> pixel px = t&31, cluster group g2 = t>>5 (8 clusters) ----
  int px = t&31, g2 = t>>5;
  float sc[8];
  #pragma unroll
  for (int kk=0;kk<8;++kk) sc[kk] = ldsL[g2*8+kk][px];
  float pm = sc[0];
  #pragma unroll
  for (int kk=1;kk<8;++kk) pm = fmaxf(pm, sc[kk]);
  redA[px][g2] = pm;
  __syncthreads();
  float m = redA[px][0];
  #pragma unroll
  for (int i=1;i<8;++i) m = fmaxf(m, redA[px][i]);
  float ps = 0.f;
  #pragma unroll
  for (int kk=0;kk<8;++kk) ps += __expf(sc[kk]-m);
  redB[px][g2] = ps;
  __syncthreads();
  float Z = 0.f;
  #pragma unroll
  for (int i=0;i<8;++i) Z += redB[px][i];
  float invZ = 1.f / Z;

  int p = p0 + px;
  int h = p/48, wc = p - h*48;
  bool h1[2], w1[2], h2[4], w2[4];
  #pragma unroll
  for (int i=0;i<2;++i){ h1[i] = (h>=16*i)&&(h<16*i+32); w1[i] = (wc>=16*i)&&(wc<16*i+32); }
  #pragma unroll
  for (int i=0;i<4;++i){ h2[i] = (h>=10*i-1)&&(h<10*i+19); w2[i] = (wc>=10*i-1)&&(wc<10*i+19); }

  #pragma unroll
  for (int kk=0;kk<8;++kk){
    int k = g2*8 + kk;
    float s0 = sc[kk];
    // shadow softmax: {s0, sh0..3} -> prob of index 0
    float sh0 = ldsL[64 + k*4 + 0][px];
    float sh1 = ldsL[64 + k*4 + 1][px];
    float sh2 = ldsL[64 + k*4 + 2][px];
    float sh3 = ldsL[64 + k*4 + 3][px];
    float m2 = fmaxf(fmaxf(fmaxf(fmaxf(s0, sh0), sh1), sh2), sh3);
    float e0 = __expf(s0-m2);
    float den = e0 + __expf(sh0-m2) + __expf(sh1-m2) + __expf(sh2-m2) + __expf(sh3-m2);
    float aval = __expf(s0-m)*invZ * (e0/den);
    a[((size_t)n*K_ + k)*P_ + p] = __float2bfloat16(aval);
    // app relu + region partial sums
    float v0 = fmaxf(ldsL[320 + k][px], 0.f);
    atomicAdd(&ldsSal[k][0], v0);
    float v1 = fmaxf(ldsL[384 + k][px], 0.f);
    #pragma unroll
    for (int i=0;i<2;++i)
      #pragma unroll
      for (int j=0;j<2;++j)
        if (h1[i] && w1[j]) atomicAdd(&ldsSal[k][1+2*i+j], v1);
    float v2 = fmaxf(ldsL[448 + k][px], 0.f);
    #pragma unroll
    for (int i=0;i<4;++i)
      #pragma unroll
      for (int j=0;j<4;++j)
        if (h2[i] && w2[j]) atomicAdd(&ldsSal[k][5+4*i+j], v2);
  }
  __syncthreads();
  float* outp = salPart + ((size_t)n*NB_ + pb)*(K_*R_);
  for (int i=t;i<K_*R_;i+=256) outp[i] = ((float*)ldsSal)[i];
}

// ---------- K3: reduce 72 per-tile partials -> sal[n][k][21] ----------
__global__ __launch_bounds__(256) void k_salred(const float* __restrict__ salPart,
                                                float* __restrict__ sal){
  int tid = blockIdx.x*256 + threadIdx.x;
  if (tid >= N_*K_*R_) return;
  int n = tid / (K_*R_), i = tid - n*(K_*R_);
  const float* sp = salPart + (size_t)n*NB_*K_*R_ + i;
  float s = 0.f;
  #pragma unroll 8
  for (int b=0;b<NB_;++b) s += sp[(size_t)b*K_*R_];
  sal[tid] = s;
}

// ---------- K4: vlad[n,k,c] = sum_p a*w*xnT[p][c] - centroid * sum(a*w) ----------
__global__ __launch_bounds__(256) void k_vlad(const bf16* __restrict__ xnT,
                                              const bf16* __restrict__ a,
                                              const float* __restrict__ sal,
                                              const void* __restrict__ cen,
                                              const int* __restrict__ flag,
                                              float* __restrict__ vlad){
  __shared__ __align__(16) float s_aw[P_];
  __shared__ float s_sal[R_];
  __shared__ __align__(16) float s_red[8][32][4];
  __shared__ float s_sumaw;
  int k = blockIdx.x, n = blockIdx.y, t = threadIdx.x;
  int f32 = flag[0];
  if (t < R_) s_sal[t] = sal[((size_t)n*K_+k)*R_ + t];
  if (t == 0) s_sumaw = 0.f;
  __syncthreads();
  const bf16* ap = a + ((size_t)n*K_+k)*P_;
  float local = 0.f;
  #pragma unroll
  for (int jj=0;jj<9;++jj){
    int p = t + jj*256;
    int h = p/48, wc = p - h*48;
    float wv = s_sal[0];
    #pragma unroll
    for (int i=0;i<2;++i) if (h>=16*i && h<16*i+32) {
      #pragma unroll
      for (int j=0;j<2;++j) if (wc>=16*j && wc<16*j+32) wv += s_sal[1+i*2+j];
    }
    #pragma unroll
    for (int i=0;i<4;++i) if (h>=10*i-1 && h<10*i+19) {
      #pragma unroll
      for (int j=0;j<4;++j) if (wc>=10*j-1 && wc<10*j+19) wv += s_sal[5+i*4+j];
    }
    float aw = b2f(ap[p])*wv;
    s_aw[p] = aw;
    local += aw;
  }
  atomicAdd(&s_sumaw, local);
  __syncthreads();
  int cg = t&31, pg = t>>5;                      // thread: 4 channels (cg*4..), pixel stride 8
  const bf16* xb = xnT + (size_t)n*P_*C_ + cg*4;
  float a0=0,a1=0,a2=0,a3=0;
  #pragma unroll 4
  for (int p=pg;p<P_;p+=8){
    ushort4 xv = *(const ushort4*)(xb + (size_t)p*C_);
    float awv = s_aw[p];
    a0 += u2f(xv.x)*awv; a1 += u2f(xv.y)*awv;
    a2 += u2f(xv.z)*awv; a3 += u2f(xv.w)*awv;
  }
  s_red[pg][cg][0]=a0; s_red[pg][cg][1]=a1; s_red[pg][cg][2]=a2; s_red[pg][cg][3]=a3;
  __syncthreads();
  if (t < C_){
    float v = 0.f;
    #pragma unroll
    for (int g=0;g<8;++g) v += ((const float*)s_red)[g*128 + t];
    float cv = f32 ? ((const float*)cen)[k*C_ + t] : b2f(((const bf16*)cen)[k*C_ + t]);
    vlad[((size_t)n*K_+k)*C_ + t] = v - cv * s_sumaw;
  }
}

// ---------- K5: intra-norm * cluster_weights, global L2 norm, store ----------
__global__ __launch_bounds__(256) void k_final(const float* __restrict__ vlad,
                                               const void* __restrict__ clw,
                                               const int* __restrict__ flag,
                                               void* __restrict__ out){
  __shared__ float s_v[K_*C_];
  __shared__ float s_ssk[K_];
  __shared__ float s_scale[K_];
  __shared__ float s_gs;
  int n = blockIdx.x, t = threadIdx.x;
  int f32 = flag[0];
  const float* vp = vlad + (size_t)n*K_*C_;
  for (int i=t;i<K_*C_;i+=256) s_v[i] = vp[i];
  __syncthreads();
  int k = t >> 2, q = t & 3;
  float ss = 0.f;
  for (int m=0;m<32;++m){ float v = s_v[k*C_ + q + 4*m]; ss += v*v; }
  ss += __shfl_down(ss, 2);
  ss += __shfl_down(ss, 1);
  if (q == 0) s_ssk[k] = ss;
  __syncthreads();
  if (t < K_){
    float cw = f32 ? ((const float*)clw)[t] : b2f(((const bf16*)clw)[t]);
    s_scale[t] = cw / fmaxf(sqrtf(s_ssk[t]), 1e-12f);
  }
  __syncthreads();
  if (t == 0){
    float gss = 0.f;
    for (int kk=0;kk<K_;++kk) gss += s_ssk[kk]*s_scale[kk]*s_scale[kk];
    s_gs = 1.f / fmaxf(sqrtf(gss), 1e-12f);
  }
  __syncthreads();
  float gsc = s_gs;
  if (f32){
    float* op = (float*)out + (size_t)n*K_*C_;
    for (int i=t;i<K_*C_;i+=256) op[i] = s_v[i]*s_scale[i>>7]*gsc;
  } else {
    bf16* op = (bf16*)out + (size_t)n*K_*C_;
    for (int i=t;i<K_*C_;i+=256) op[i] = __float2bfloat16(s_v[i]*s_scale[i>>7]*gsc);
  }
}

extern "C" void kernel_launch(void* const* d_in, const int* in_sizes, int n_in,
                              void* d_out, int out_size, void* d_ws, size_t ws_size,
                              hipStream_t stream){
  const void* x   = d_in[0];
  const void* cen = d_in[1];
  const void* cvw = d_in[2];
  const void* csw = d_in[3];
  const void* caw = d_in[4];
  const void* clw = d_in[5];

  char* ws = (char*)d_ws;
  int*  flag    = (int*)ws;    ws += 256;
  bf16* Wall    = (bf16*)ws;   ws += (size_t)M_*C_*2;          // 128 KB
  bf16* xnT     = (bf16*)ws;   ws += (size_t)N_*P_*C_*2;       // 18.87 MB
  bf16* a       = (bf16*)ws;   ws += (size_t)N_*K_*P_*2;       //  9.44 MB
  float* salPart= (float*)ws;  ws += (size_t)N_*NB_*K_*R_*4;   // 12.39 MB
  float* sal    = (float*)ws;  ws += (size_t)N_*K_*R_*4;       //  0.17 MB
  float* vlad   = (float*)ws;  ws += (size_t)N_*K_*C_*4;       //  1.05 MB

  k_probe <<<dim3(1),                  256, 0, stream>>>((const unsigned short*)x, flag);
  k_wall  <<<dim3(M_*C_/256),          256, 0, stream>>>(cvw, csw, caw, flag, Wall);
  k_norm  <<<dim3((N_*P_)/256),        256, 0, stream>>>(x, flag, xnT);
  k_gemm  <<<dim3(NB_, N_),            256, 0, stream>>>(Wall, xnT, a, salPart);
  k_salred<<<dim3((N_*K_*R_+255)/256), 256, 0, stream>>>(salPart, sal);
  k_vlad  <<<dim3(K_, N_),             256, 0, stream>>>(xnT, a, sal, cen, flag, vlad);
  k_final <<<dim3(N_),                 256, 0, stream>>>(vlad, clw, flag, d_out);
}

// Round 4
// 232.105 us; speedup vs baseline: 3.7401x; 1.7411x over previous
//
#include <hip/hip_runtime.h>
#include <hip/hip_bf16.h>

#define N_ 32
#define C_ 128
#define H_ 48
#define W_ 48
#define P_ (H_*W_)   // 2304
#define K_ 64
#define S_ 4
#define L_ 3
#define R_ 21
#define NB_ 72       // P_/32 pixel tiles per image
#define M_ 512       // total logit rows

typedef __hip_bfloat16 bf16;
typedef __attribute__((ext_vector_type(8))) short   bf16x8;
typedef __attribute__((ext_vector_type(8))) unsigned short u16x8;
typedef __attribute__((ext_vector_type(4))) float   f32x4;

__device__ __forceinline__ float b2f(bf16 v){ return __bfloat162float(v); }
__device__ __forceinline__ float u2f(unsigned short u){
  union { unsigned i; float f; } v; v.i = ((unsigned)u) << 16; return v.f;
}
__device__ __forceinline__ unsigned short f2u(float f){
  bf16 h = __float2bfloat16(f);
  return *(unsigned short*)&h;
}

// ---------- dtype probe: flag=1 if inputs are fp32, 0 if bf16 ----------
__global__ __launch_bounds__(256) void k_probe(const unsigned short* __restrict__ xb,
                                               int* __restrict__ flag){
  int t = threadIdx.x;
  int weird = 0;
  for (int i = t; i < 4096; i += 256){
    int e = (xb[i] >> 7) & 0xFF;
    if (e >= 0x8E) weird++;
  }
  __shared__ int s[256];
  s[t] = weird; __syncthreads();
  for (int o = 128; o > 0; o >>= 1){ if (t < o) s[t] += s[t+o]; __syncthreads(); }
  if (t == 0) flag[0] = (s[0] > 64) ? 1 : 0;
}

// ---------- build Wall[512][128] bf16: rows 0-63 score, 64-319 shadow, 320-511 app ----------
__global__ __launch_bounds__(256) void k_wall(const void* __restrict__ cvw, const void* __restrict__ csw,
                                              const void* __restrict__ caw, const int* __restrict__ flag,
                                              bf16* __restrict__ Wall){
  int i = blockIdx.x*256 + threadIdx.x;          // 0..65535
  int f32 = flag[0];
  float v;
  if (i < 8192)       v = f32 ? ((const float*)cvw)[i]        : b2f(((const bf16*)cvw)[i]);
  else if (i < 40960) v = f32 ? ((const float*)csw)[i-8192]   : b2f(((const bf16*)csw)[i-8192]);
  else                v = f32 ? ((const float*)caw)[i-40960]  : b2f(((const bf16*)caw)[i-40960]);
  Wall[i] = __float2bfloat16(v);
}

// ---------- K1: per-pixel L2 norm -> xnT[n][p][c] bf16 (pixel-major, MFMA-B-ready) ----------
__global__ __launch_bounds__(256) void k_norm(const void* __restrict__ x,
                                              const int* __restrict__ flag,
                                              bf16* __restrict__ xnT){
  int idx = blockIdx.x*256 + threadIdx.x;        // n*P + p
  int n = idx / P_, p = idx - n*P_;
  int f32 = flag[0];
  float ss = 0.f;
  if (f32){
    const float* xc = (const float*)x + (size_t)n*C_*P_ + p;
    #pragma unroll 8
    for (int c=0;c<C_;++c){ float v = xc[(size_t)c*P_]; ss += v*v; }
    float invn = 1.f / fmaxf(sqrtf(ss), 1e-12f);
    bf16* xo = xnT + ((size_t)n*P_ + p)*C_;
    for (int c8=0;c8<C_;c8+=8){
      u16x8 pk;
      #pragma unroll
      for (int j=0;j<8;++j) pk[j] = f2u(xc[(size_t)(c8+j)*P_] * invn);
      *(u16x8*)(xo + c8) = pk;
    }
  } else {
    const bf16* xc = (const bf16*)x + (size_t)n*C_*P_ + p;
    #pragma unroll 8
    for (int c=0;c<C_;++c){ float v = b2f(xc[(size_t)c*P_]); ss += v*v; }
    float invn = 1.f / fmaxf(sqrtf(ss), 1e-12f);
    bf16* xo = xnT + ((size_t)n*P_ + p)*C_;
    for (int c8=0;c8<C_;c8+=8){
      u16x8 pk;
      #pragma unroll
      for (int j=0;j<8;++j) pk[j] = f2u(b2f(xc[(size_t)(c8+j)*P_]) * invn);
      *(u16x8*)(xo + c8) = pk;
    }
  }
}

// ---------- K2: fused 512-row MFMA GEMM; score+shadow -> LDS softmax; app -> relu -> global g ----------
// grid (NB_=72, N_=32), 256 threads (4 waves). Wave w owns rows [w*128, w*128+128).
__global__ __launch_bounds__(256, 3) void k_gemm(const bf16* __restrict__ Wall,
                                                 const bf16* __restrict__ xnT,
                                                 bf16* __restrict__ a,
                                                 bf16* __restrict__ g){
  __shared__ float ldsL[320][34];                // 43520 B (score+shadow only)
  __shared__ float redA[32][8];
  __shared__ float redB[32][8];
  int n = blockIdx.y, pb = blockIdx.x;
  int p0 = pb*32;
  int t = threadIdx.x, w = t>>6, l = t&63;

  int mrow = l&15, quad = l>>4;
  const bf16* Abase = Wall + ((size_t)(w*128 + mrow))*C_ + quad*8;
  const bf16* Bbase = xnT + ((size_t)n*P_ + p0 + mrow)*C_ + quad*8;

  f32x4 acc[8][2];
  #pragma unroll
  for (int rt=0;rt<8;++rt){ acc[rt][0] = (f32x4){0,0,0,0}; acc[rt][1] = (f32x4){0,0,0,0}; }

  #pragma unroll
  for (int k0=0;k0<C_;k0+=32){
    bf16x8 b0 = *(const bf16x8*)(Bbase + k0);
    bf16x8 b1 = *(const bf16x8*)(Bbase + 16*C_ + k0);
    #pragma unroll
    for (int rt=0;rt<8;++rt){
      bf16x8 af = *(const bf16x8*)(Abase + (size_t)rt*16*C_ + k0);
      acc[rt][0] = __builtin_amdgcn_mfma_f32_16x16x32_bf16(af, b0, acc[rt][0], 0,0,0);
      acc[rt][1] = __builtin_amdgcn_mfma_f32_16x16x32_bf16(af, b1, acc[rt][1], 0,0,0);
    }
  }
  // C/D layout: col = lane&15, row = quad*4 + reg
  #pragma unroll
  for (int rt=0;rt<8;++rt){
    int row0 = w*128 + rt*16;                    // wave-uniform
    if (row0 < 320){
      #pragma unroll
      for (int ct=0;ct<2;++ct)
        #pragma unroll
        for (int r=0;r<4;++r)
          ldsL[row0 + quad*4 + r][ct*16 + mrow] = acc[rt][ct][r];
    } else {
      int lk0 = row0 - 320 + quad*4;
      #pragma unroll
      for (int ct=0;ct<2;++ct)
        #pragma unroll
        for (int r=0;r<4;++r)
          g[((size_t)n*192 + lk0 + r)*P_ + p0 + ct*16 + mrow] =
              __float2bfloat16(fmaxf(acc[rt][ct][r], 0.f));
    }
  }
  __syncthreads();

  // ---- epilogue: thread t -> pixel px = t&31, cluster group g2 = t>>5 (8 clusters) ----
  int px = t&31, g2 = t>>5;
  float sc[8];
  #pragma unroll
  for (int kk=0;kk<8;++kk) sc[kk] = ldsL[g2*8+kk][px];
  float pm = sc[0];
  #pragma unroll
  for (int kk=1;kk<8;++kk) pm = fmaxf(pm, sc[kk]);
  redA[px][g2] = pm;
  __syncthreads();
  float m = redA[px][0];
  #pragma unroll
  for (int i=1;i<8;++i) m = fmaxf(m, redA[px][i]);
  float ps = 0.f;
  #pragma unroll
  for (int kk=0;kk<8;++kk) ps += __expf(sc[kk]-m);
  redB[px][g2] = ps;
  __syncthreads();
  float Z = 0.f;
  #pragma unroll
  for (int i=0;i<8;++i) Z += redB[px][i];
  float invZ = 1.f / Z;

  int p = p0 + px;
  #pragma unroll
  for (int kk=0;kk<8;++kk){
    int k = g2*8 + kk;
    float s0 = sc[kk];
    float sh0 = ldsL[64 + k*4 + 0][px];
    float sh1 = ldsL[64 + k*4 + 1][px];
    float sh2 = ldsL[64 + k*4 + 2][px];
    float sh3 = ldsL[64 + k*4 + 3][px];
    float m2 = fmaxf(fmaxf(fmaxf(fmaxf(s0, sh0), sh1), sh2), sh3);
    float e0 = __expf(s0-m2);
    float den = e0 + __expf(sh0-m2) + __expf(sh1-m2) + __expf(sh2-m2) + __expf(sh3-m2);
    float aval = __expf(s0-m)*invZ * (e0/den);
    a[((size_t)n*K_ + k)*P_ + p] = __float2bfloat16(aval);
  }
}

// ---------- K3: region sums from g -> sal[n][k][21]. One block per (n,k), no atomics. ----------
__global__ __launch_bounds__(256) void k_sal2(const bf16* __restrict__ g, float* __restrict__ sal){
  int k = blockIdx.x, n = blockIdx.y, t = threadIdx.x;
  const bf16* g0 = g + ((size_t)n*192 + k)*P_;
  const bf16* g1 = g0 + (size_t)64*P_;
  const bf16* g2p = g0 + (size_t)128*P_;
  float acc[R_];
  #pragma unroll
  for (int r=0;r<R_;++r) acc[r] = 0.f;
  #pragma unroll
  for (int jj=0;jj<9;++jj){
    int p = t + jj*256;
    int h = p/48, wc = p - h*48;
    acc[0] += b2f(g0[p]);
    float v1 = b2f(g1[p]);
    #pragma unroll
    for (int i=0;i<2;++i) if (h>=16*i && h<16*i+32)
      #pragma unroll
      for (int j=0;j<2;++j) if (wc>=16*j && wc<16*j+32) acc[1+2*i+j] += v1;
    float v2 = b2f(g2p[p]);
    #pragma unroll
    for (int i=0;i<4;++i) if (h>=10*i-1 && h<10*i+19)
      #pragma unroll
      for (int j=0;j<4;++j) if (wc>=10*j-1 && wc<10*j+19) acc[5+4*i+j] += v2;
  }
  #pragma unroll
  for (int r=0;r<R_;++r){
    float v = acc[r];
    #pragma unroll
    for (int o=32;o>0;o>>=1) v += __shfl_down(v, o);
    acc[r] = v;
  }
  __shared__ float s_part[4][R_];
  int wv = t>>6;
  if ((t&63) == 0){
    #pragma unroll
    for (int r=0;r<R_;++r) s_part[wv][r] = acc[r];
  }
  __syncthreads();
  if (t < R_)
    sal[((size_t)n*K_+k)*R_ + t] = s_part[0][t]+s_part[1][t]+s_part[2][t]+s_part[3][t];
}

// ---------- K4: vlad for 2 clusters per block ----------
__global__ __launch_bounds__(256) void k_vlad(const bf16* __restrict__ xnT,
                                              const bf16* __restrict__ a,
                                              const float* __restrict__ sal,
                                              const void* __restrict__ cen,
                                              const int* __restrict__ flag,
                                              float* __restrict__ vlad){
  __shared__ __align__(16) float s_aw[2][P_];    // 18432 B
  __shared__ float s_sal[2][R_];
  __shared__ __align__(16) float s_red[8][32][4];
  __shared__ float s_saw[2][4];
  int kp = blockIdx.x, n = blockIdx.y, t = threadIdx.x;
  int k0 = kp*2;
  int f32 = flag[0];
  if (t < 2*R_) ((float*)s_sal)[t] = sal[((size_t)n*K_+k0)*R_ + t];
  __syncthreads();
  const bf16* ap0 = a + ((size_t)n*K_+k0)*P_;
  const bf16* ap1 = ap0 + P_;
  float loc0 = 0.f, loc1 = 0.f;
  #pragma unroll
  for (int jj=0;jj<9;++jj){
    int p = t + jj*256;
    int h = p/48, wc = p - h*48;
    float w0 = s_sal[0][0], w1 = s_sal[1][0];
    #pragma unroll
    for (int i=0;i<2;++i) if (h>=16*i && h<16*i+32)
      #pragma unroll
      for (int j=0;j<2;++j) if (wc>=16*j && wc<16*j+32){
        w0 += s_sal[0][1+2*i+j]; w1 += s_sal[1][1+2*i+j];
      }
    #pragma unroll
    for (int i=0;i<4;++i) if (h>=10*i-1 && h<10*i+19)
      #pragma unroll
      for (int j=0;j<4;++j) if (wc>=10*j-1 && wc<10*j+19){
        w0 += s_sal[0][5+4*i+j]; w1 += s_sal[1][5+4*i+j];
      }
    float aw0 = b2f(ap0[p])*w0; s_aw[0][p] = aw0; loc0 += aw0;
    float aw1 = b2f(ap1[p])*w1; s_aw[1][p] = aw1; loc1 += aw1;
  }
  #pragma unroll
  for (int o=32;o>0;o>>=1){ loc0 += __shfl_down(loc0,o); loc1 += __shfl_down(loc1,o); }
  if ((t&63) == 0){ s_saw[0][t>>6] = loc0; s_saw[1][t>>6] = loc1; }
  __syncthreads();

  int cg = t&31, pg = t>>5;                      // thread: 4 channels, pixel stride 8
  const bf16* xb = xnT + (size_t)n*P_*C_ + cg*4;
  float a0=0,a1=0,a2=0,a3=0, b0=0,b1=0,b2=0,b3=0;
  #pragma unroll 4
  for (int p=pg;p<P_;p+=8){
    ushort4 xv = *(const ushort4*)(xb + (size_t)p*C_);
    float f0=u2f(xv.x), f1=u2f(xv.y), f2=u2f(xv.z), f3=u2f(xv.w);
    float w0 = s_aw[0][p], w1 = s_aw[1][p];
    a0 += f0*w0; a1 += f1*w0; a2 += f2*w0; a3 += f3*w0;
    b0 += f0*w1; b1 += f1*w1; b2 += f2*w1; b3 += f3*w1;
  }
  float sumaw0 = s_saw[0][0]+s_saw[0][1]+s_saw[0][2]+s_saw[0][3];
  float sumaw1 = s_saw[1][0]+s_saw[1][1]+s_saw[1][2]+s_saw[1][3];
  s_red[pg][cg][0]=a0; s_red[pg][cg][1]=a1; s_red[pg][cg][2]=a2; s_red[pg][cg][3]=a3;
  __syncthreads();
  if (t < C_){
    float v = 0.f;
    #pragma unroll
    for (int gg=0;gg<8;++gg) v += ((const float*)s_red)[gg*128 + t];
    float cv = f32 ? ((const float*)cen)[k0*C_ + t] : b2f(((const bf16*)cen)[k0*C_ + t]);
    vlad[((size_t)n*K_+k0)*C_ + t] = v - cv * sumaw0;
  }
  __syncthreads();
  s_red[pg][cg][0]=b0; s_red[pg][cg][1]=b1; s_red[pg][cg][2]=b2; s_red[pg][cg][3]=b3;
  __syncthreads();
  if (t < C_){
    float v = 0.f;
    #pragma unroll
    for (int gg=0;gg<8;++gg) v += ((const float*)s_red)[gg*128 + t];
    float cv = f32 ? ((const float*)cen)[(k0+1)*C_ + t] : b2f(((const bf16*)cen)[(k0+1)*C_ + t]);
    vlad[((size_t)n*K_+k0+1)*C_ + t] = v - cv * sumaw1;
  }
}

// ---------- K5: intra-norm * cluster_weights, global L2 norm, store ----------
__global__ __launch_bounds__(256) void k_final(const float* __restrict__ vlad,
                                               const void* __restrict__ clw,
                                               const int* __restrict__ flag,
                                               void* __restrict__ out){
  __shared__ float s_v[K_*C_];
  __shared__ float s_ssk[K_];
  __shared__ float s_scale[K_];
  __shared__ float s_gs;
  int n = blockIdx.x, t = threadIdx.x;
  int f32 = flag[0];
  const float* vp = vlad + (size_t)n*K_*C_;
  for (int i=t;i<K_*C_;i+=256) s_v[i] = vp[i];
  __syncthreads();
  int k = t >> 2, q = t & 3;
  float ss = 0.f;
  for (int m=0;m<32;++m){ float v = s_v[k*C_ + q + 4*m]; ss += v*v; }
  ss += __shfl_down(ss, 2);
  ss += __shfl_down(ss, 1);
  if (q == 0) s_ssk[k] = ss;
  __syncthreads();
  if (t < K_){
    float cw = f32 ? ((const float*)clw)[t] : b2f(((const bf16*)clw)[t]);
    s_scale[t] = cw / fmaxf(sqrtf(s_ssk[t]), 1e-12f);
  }
  __syncthreads();
  if (t == 0){
    float gss = 0.f;
    for (int kk=0;kk<K_;++kk) gss += s_ssk[kk]*s_scale[kk]*s_scale[kk];
    s_gs = 1.f / fmaxf(sqrtf(gss), 1e-12f);
  }
  __syncthreads();
  float gsc = s_gs;
  if (f32){
    float* op = (float*)out + (size_t)n*K_*C_;
    for (int i=t;i<K_*C_;i+=256) op[i] = s_v[i]*s_scale[i>>7]*gsc;
  } else {
    bf16* op = (bf16*)out + (size_t)n*K_*C_;
    for (int i=t;i<K_*C_;i+=256) op[i] = __float2bfloat16(s_v[i]*s_scale[i>>7]*gsc);
  }
}

extern "C" void kernel_launch(void* const* d_in, const int* in_sizes, int n_in,
                              void* d_out, int out_size, void* d_ws, size_t ws_size,
                              hipStream_t stream){
  const void* x   = d_in[0];
  const void* cen = d_in[1];
  const void* cvw = d_in[2];
  const void* csw = d_in[3];
  const void* caw = d_in[4];
  const void* clw = d_in[5];

  char* ws = (char*)d_ws;
  int*  flag  = (int*)ws;    ws += 256;
  bf16* Wall  = (bf16*)ws;   ws += (size_t)M_*C_*2;          // 128 KB
  bf16* xnT   = (bf16*)ws;   ws += (size_t)N_*P_*C_*2;       // 18.87 MB
  bf16* a     = (bf16*)ws;   ws += (size_t)N_*K_*P_*2;       //  9.44 MB
  bf16* g     = (bf16*)ws;   ws += (size_t)N_*192*P_*2;      // 28.31 MB
  float* sal  = (float*)ws;  ws += (size_t)N_*K_*R_*4;       //  0.17 MB
  float* vlad = (float*)ws;  ws += (size_t)N_*K_*C_*4;       //  1.05 MB

  k_probe <<<dim3(1),           256, 0, stream>>>((const unsigned short*)x, flag);
  k_wall  <<<dim3(M_*C_/256),   256, 0, stream>>>(cvw, csw, caw, flag, Wall);
  k_norm  <<<dim3((N_*P_)/256), 256, 0, stream>>>(x, flag, xnT);
  k_gemm  <<<dim3(NB_, N_),     256, 0, stream>>>(Wall, xnT, a, g);
  k_sal2  <<<dim3(K_, N_),      256, 0, stream>>>(g, sal);
  k_vlad  <<<dim3(K_/2, N_),    256, 0, stream>>>(xnT, a, sal, cen, flag, vlad);
  k_final <<<dim3(N_),          256, 0, stream>>>(vlad, clw, flag, d_out);
}